// Round 1
// baseline (263.041 us; speedup 1.0000x reference)
//
#include <hip/hip_runtime.h>
#include <math.h>

// DETR HungarianMatcher cost matrix:
//   C[n,t] = W_BBOX * L1(pred_box[n], tgt_box[t])
//          + W_CLASS * (pos - neg)(sigmoid(logits[n, tgt_ids[t]]))
//          - W_GIOU * GIoU(xyxy(pred_box[n]), xyxy(tgt_box[t]))
// N = bs*Q = 14400, T = 4096, C = 91. Output 236 MB fp32 -> write-BW bound.
//
// Factorization: class cost depends only on (n, class_id) -> compute the
// [NROWS x C] table into LDS once per block; per-element work is an LDS
// gather + ~40 fp32 box ops.

#define ALPHA_  0.25f
#define EPS_    1e-8f
#define W_CLASS 2.0f
#define W_BBOX  5.0f
#define W_GIOU  2.0f

#define TPB    256   // threads per block
#define TVEC   4     // targets per thread (float4 store)
#define NROWS  16    // pred rows per block
#define CMAX   256   // max supported num classes (actual C = 91)

__device__ __forceinline__ float fast_rcp(float x) {
#if __has_builtin(__builtin_amdgcn_rcpf)
    return __builtin_amdgcn_rcpf(x);
#else
    return 1.0f / x;
#endif
}

__global__ __launch_bounds__(TPB) void matcher_cost_kernel(
    const float* __restrict__ logits,  // [N, C]
    const float* __restrict__ pboxes,  // [N, 4] cxcywh
    const int*   __restrict__ tids,    // [T]
    const float* __restrict__ tboxes,  // [T, 4] cxcywh
    float* __restrict__ out,           // [N, T]
    int N, int C, int T)
{
    __shared__ float lds_cc[NROWS * CMAX];  // class-cost table for this block's rows

    const int nbase = blockIdx.y * NROWS;
    const int rows  = min(NROWS, N - nbase);

    // ---- Stage class-cost table: cc[r][c] = pos - neg for n = nbase + r ----
    for (int i = threadIdx.x; i < rows * C; i += TPB) {
        const int r = i / C;
        const int c = i - r * C;
        const float x  = logits[(size_t)(nbase + r) * C + c];
        const float e  = __expf(-x);
        const float p  = fast_rcp(1.0f + e);         // sigmoid
        const float om = 1.0f - p;
        const float pos = ALPHA_ * om * om * (-__logf(p + EPS_));
        const float neg = (1.0f - ALPHA_) * p * p * (-__logf(om + EPS_));
        lds_cc[i] = pos - neg;                       // stride == C (i = r*C + c)
    }
    __syncthreads();

    // ---- Load this thread's 4 targets into registers (reused for all rows) ----
    const int t0 = blockIdx.x * (TPB * TVEC) + threadIdx.x * TVEC;
    if (t0 + TVEC > T) return;  // T is a multiple of 1024 in this problem

    int   tid_[TVEC];
    float tcx[TVEC], tcy[TVEC], tw_[TVEC], th_[TVEC];
    float tx0[TVEC], ty0[TVEC], tx1[TVEC], ty1[TVEC], ta_[TVEC];

    {
        const int4 id4 = *(const int4*)(tids + t0);
        tid_[0] = id4.x; tid_[1] = id4.y; tid_[2] = id4.z; tid_[3] = id4.w;
#pragma unroll
        for (int j = 0; j < TVEC; ++j) {
            const float4 tb = *(const float4*)(tboxes + (size_t)(t0 + j) * 4);
            tcx[j] = tb.x; tcy[j] = tb.y; tw_[j] = tb.z; th_[j] = tb.w;
            tx0[j] = tb.x - 0.5f * tb.z;
            ty0[j] = tb.y - 0.5f * tb.w;
            tx1[j] = tb.x + 0.5f * tb.z;
            ty1[j] = tb.y + 0.5f * tb.w;
            ta_[j] = tb.z * tb.w;
        }
    }

    // ---- Row loop: one pred box per iteration, 4 outputs, one float4 store ----
    for (int r = 0; r < rows; ++r) {
        const int n = nbase + r;
        const float4 pb = *(const float4*)(pboxes + (size_t)n * 4);  // uniform -> scalar path
        const float pcx = pb.x, pcy = pb.y, pw = pb.z, ph = pb.w;
        const float px0 = pcx - 0.5f * pw, py0 = pcy - 0.5f * ph;
        const float px1 = pcx + 0.5f * pw, py1 = pcy + 0.5f * ph;
        const float pa  = pw * ph;
        const float* ccrow = &lds_cc[r * C];

        float4 o;
        float* op = &o.x;
#pragma unroll
        for (int j = 0; j < TVEC; ++j) {
            // L1 on raw cxcywh
            const float l1 = fabsf(pcx - tcx[j]) + fabsf(pcy - tcy[j])
                           + fabsf(pw  - tw_[j]) + fabsf(ph  - th_[j]);
            // intersection
            const float ltx = fmaxf(px0, tx0[j]), lty = fmaxf(py0, ty0[j]);
            const float rbx = fminf(px1, tx1[j]), rby = fminf(py1, ty1[j]);
            const float iw = fmaxf(rbx - ltx, 0.0f);
            const float ih = fmaxf(rby - lty, 0.0f);
            const float inter = iw * ih;
            const float uni = pa + ta_[j] - inter;
            // enclosing box
            const float ex0 = fminf(px0, tx0[j]), ey0 = fminf(py0, ty0[j]);
            const float ex1 = fmaxf(px1, tx1[j]), ey1 = fmaxf(py1, ty1[j]);
            const float ew = fmaxf(ex1 - ex0, 0.0f);
            const float eh = fmaxf(ey1 - ey0, 0.0f);
            const float ea = ew * eh;
            const float giou = inter * fast_rcp(uni) - (ea - uni) * fast_rcp(ea);
            // class cost gather (LDS)
            const float cc = ccrow[tid_[j]];
            op[j] = W_BBOX * l1 + W_CLASS * cc - W_GIOU * giou;
        }
        *(float4*)(out + (size_t)n * T + t0) = o;
    }
}

extern "C" void kernel_launch(void* const* d_in, const int* in_sizes, int n_in,
                              void* d_out, int out_size, void* d_ws, size_t ws_size,
                              hipStream_t stream) {
    const float* logits = (const float*)d_in[0];  // [N, C]
    const float* pboxes = (const float*)d_in[1];  // [N, 4]
    const int*   tids   = (const int*)  d_in[2];  // [T]
    const float* tboxes = (const float*)d_in[3];  // [T, 4]
    float* out = (float*)d_out;

    const int N = in_sizes[1] / 4;          // 14400
    const int C = in_sizes[0] / N;          // 91
    const int T = in_sizes[2];              // 4096

    dim3 grid((T + TPB * TVEC - 1) / (TPB * TVEC),   // 4
              (N + NROWS - 1) / NROWS);              // 900
    matcher_cost_kernel<<<grid, TPB, 0, stream>>>(logits, pboxes, tids, tboxes,
                                                  out, N, C, T);
}

// Round 3
// 262.087 us; speedup vs baseline: 1.0036x; 1.0036x over previous
//
#include <hip/hip_runtime.h>
#include <math.h>

// DETR HungarianMatcher cost matrix.
// N = bs*Q = 14400, T = 4096, C = 91. Output [N,T] fp32 = 236 MB -> write-BW bound.
//
// R3 = R2 intent with fixed codegen-safe structure:
//  - per-target state in fully-unrolled constant-index arrays (SROA -> registers)
//  - single v_rcp per element: inter/uni + uni/ea = (inter*ea + uni^2)/(uni*ea)
//  - min3/max3 center/size box math, reuses L1 |dx|,|dy| (~33 VALU/elem)
//  - nontemporal float4 stores (write-once 236 MB stream)
//  - LDS class table padded to stride 96

#define ALPHA_  0.25f
#define EPS_    1e-8f

#define TPB    256   // threads per block
#define TVEC   4     // targets per thread (one float4 store)
#define NROWS  16    // pred rows per block
#define CPAD   96    // padded class stride (C = 91 actual)

typedef float f32x4 __attribute__((ext_vector_type(4)));

__device__ __forceinline__ float fast_rcp(float x) {
    return __builtin_amdgcn_rcpf(x);
}

__global__ __launch_bounds__(TPB) void matcher_cost_kernel(
    const float* __restrict__ logits,  // [N, C]
    const float* __restrict__ pboxes,  // [N, 4] cxcywh
    const int*   __restrict__ tids,    // [T]
    const float* __restrict__ tboxes,  // [T, 4] cxcywh
    float* __restrict__ out,           // [N, T]
    int N, int C, int T)
{
    __shared__ float lds_cc[NROWS * CPAD];  // per-row class-cost table

    const int nbase = blockIdx.y * NROWS;
    const int rows  = min(NROWS, N - nbase);

    // ---- Stage class-cost table: cc[r][c] = pos - neg, focal-style ----
    for (int i = threadIdx.x; i < NROWS * CPAD; i += TPB) {
        const int r = i / CPAD;          // compile-time const divisor -> magic mul
        const int c = i - r * CPAD;
        if (r < rows && c < C) {
            const float x  = logits[(size_t)(nbase + r) * C + c];
            const float p  = fast_rcp(1.0f + __expf(-x));   // sigmoid
            const float om = 1.0f - p;
            const float pos = ALPHA_ * om * om * (-__logf(p + EPS_));
            const float neg = (1.0f - ALPHA_) * p * p * (-__logf(om + EPS_));
            lds_cc[i] = pos - neg;
        }
    }
    __syncthreads();

    const int t0 = blockIdx.x * (TPB * TVEC) + threadIdx.x * TVEC;
    if (t0 + TVEC > T) return;   // T = 4096: never taken; no barriers below

    // ---- This thread's 4 targets (constant-index arrays -> registers) ----
    const int4 id4 = *(const int4*)(tids + t0);
    int tid_[TVEC] = { id4.x, id4.y, id4.z, id4.w };

    float tcx[TVEC], tcy[TVEC], tw_[TVEC], th_[TVEC];
    float twh[TVEC], thh[TVEC], ta_[TVEC];
#pragma unroll
    for (int j = 0; j < TVEC; ++j) {
        const float4 tb = *(const float4*)(tboxes + (size_t)(t0 + j) * 4);
        tcx[j] = tb.x;  tcy[j] = tb.y;
        tw_[j] = tb.z;  th_[j] = tb.w;
        twh[j] = 0.5f * tb.z;
        thh[j] = 0.5f * tb.w;
        ta_[j] = tb.z * tb.w;
    }

    float* orow = out + t0;

    for (int r = 0; r < rows; ++r) {
        const int n = nbase + r;
        const float4 pb = *(const float4*)(pboxes + (size_t)n * 4);  // uniform addr
        const float pcx = pb.x, pcy = pb.y, pw = pb.z, ph = pb.w;
        const float pwh = 0.5f * pw, phh = 0.5f * ph;
        const float pa  = pw * ph;
        const float* ccrow = &lds_cc[r * CPAD];

        f32x4 o;
#pragma unroll
        for (int j = 0; j < TVEC; ++j) {
            const float adx = fabsf(pcx - tcx[j]);
            const float ady = fabsf(pcy - tcy[j]);
            const float l1  = adx + ady + fabsf(pw - tw_[j]) + fabsf(ph - th_[j]);
            const float sx  = pwh + twh[j], sy = phh + thh[j];
            // overlap along an axis: min(pw, tw, sx - |dx|); enclosure: max(pw, tw, sx + |dx|)
            const float iw = fmaxf(fminf(fminf(pw, tw_[j]), sx - adx), 0.0f);
            const float ih = fmaxf(fminf(fminf(ph, th_[j]), sy - ady), 0.0f);
            const float ew = fmaxf(fmaxf(pw, tw_[j]), sx + adx);
            const float eh = fmaxf(fmaxf(ph, th_[j]), sy + ady);
            const float inter = iw * ih;
            const float uni   = pa + ta_[j] - inter;
            const float ea    = ew * eh;
            // g = inter/uni + uni/ea ; giou = g - 1
            const float num = fmaf(inter, ea, uni * uni);
            const float g   = num * fast_rcp(uni * ea);
            const float cc  = ccrow[tid_[j]];
            o[j] = fmaf(5.0f, l1, fmaf(2.0f, cc, fmaf(-2.0f, g, 2.0f)));
        }

        __builtin_nontemporal_store(o, (f32x4*)(orow + (size_t)n * T));
    }
}

extern "C" void kernel_launch(void* const* d_in, const int* in_sizes, int n_in,
                              void* d_out, int out_size, void* d_ws, size_t ws_size,
                              hipStream_t stream) {
    const float* logits = (const float*)d_in[0];  // [N, C]
    const float* pboxes = (const float*)d_in[1];  // [N, 4]
    const int*   tids   = (const int*)  d_in[2];  // [T]
    const float* tboxes = (const float*)d_in[3];  // [T, 4]
    float* out = (float*)d_out;

    const int N = in_sizes[1] / 4;          // 14400
    const int C = in_sizes[0] / N;          // 91
    const int T = in_sizes[2];              // 4096

    dim3 grid((T + TPB * TVEC - 1) / (TPB * TVEC),   // 4
              (N + NROWS - 1) / NROWS);              // 900
    matcher_cost_kernel<<<grid, TPB, 0, stream>>>(logits, pboxes, tids, tboxes,
                                                  out, N, C, T);
}